// Round 12
// baseline (1839.236 us; speedup 1.0000x reference)
//
#include <hip/hip_runtime.h>
#include <math.h>

#define BB 4
#define LF 257      // NTOK+1
#define DMODEL 384
#define DIN 768
#define NST 16
#define DTR 24
#define XDB 56      // DTR + 2*N
#define POSROW 128
#define CL 16       // scan chunk length
#define NC 17       // ceil(LF/CL)
#define MROWS (BB * LF)   // 1028

typedef __attribute__((ext_vector_type(8))) short short8;
typedef __attribute__((ext_vector_type(4))) float f32x4;

__device__ __forceinline__ float siluf(float v) { return v / (1.f + __expf(-v)); }
__device__ __forceinline__ float softplusf(float v) {
    return (v > 20.f) ? v : log1pf(__expf(v));
}
__device__ __forceinline__ short f2bf(float f) {
    unsigned u = __builtin_bit_cast(unsigned, f);
    unsigned r = (u + 0x7FFFu + ((u >> 16) & 1u)) >> 16;
    return (short)r;
}

struct MP {
    const float *depth_seq, *state_vec, *action, *patch_w, *patch_b;
    const float *cls_token, *pos_embed;
    const float *ln_w, *ln_b, *in_proj_w, *conv_w, *conv_b, *conv_wb, *conv_bb;
    const float *xproj_w, *xproj_wb, *dtproj_w, *dtproj_b, *dtproj_wb, *dtproj_bb;
    const float *A_log, *A_logb, *Dp, *Dpb, *out_w, *lnf_w, *lnf_b;
    const float *cw1, *cb1, *cw2, *cb2;
    float *residual, *xz, *xcf, *xcb, *xdbf, *xdbb, *yfb, *ybb, *hpart, *sumd;
    int* flags;
    float* out;
};

// ---------------------------------------------------------------------------
// bf16-MFMA 64x64 GEMM tile over K range [kb,ke). 4 waves (2x2), each wave
// 2x2 mfma_f32_16x16x32_bf16. f32 global -> RNE bf16 -> LDS fragment order.
// AMODE: 1 patch gather, 2 flip-add, 3 LN-fused (gA = LDS stats[64]{mean,rstd},
//        A2=lnw, pos=lnb).  SMODE: 0 plain(+bias), 3 patchify store, 4 atomicAdd
// ---------------------------------------------------------------------------
template<int AMODE, int SMODE>
__device__ void gemm_tile(
    const float* __restrict__ A, int lda,
    const float* __restrict__ W,
    const float* __restrict__ bias,
    float* __restrict__ Cout, int M, int N, int K, int kb, int ke,
    int bm, int bn,
    const float* __restrict__ gA, const float* __restrict__ A2,
    const float* __restrict__ pos,
    short* __restrict__ Ab, short* __restrict__ Wb)
{
    const int tid = threadIdx.x;
    const int m_s = tid >> 2;
    const int q_s = tid & 3;
    const int lane = tid & 63;
    const int wv = tid >> 6;
    const int wm = (wv >> 1) * 32, wn = (wv & 1) * 32;
    const int qq = lane >> 4, lr = lane & 15;

    f32x4 acc[2][2];
    #pragma unroll
    for (int i = 0; i < 2; ++i)
        #pragma unroll
        for (int j = 0; j < 2; ++j)
            acc[i][j] = f32x4{0.f, 0.f, 0.f, 0.f};

    float4 pa[2], pw[2];
    const float4 z4 = make_float4(0.f, 0.f, 0.f, 0.f);

    auto loadA = [&](int k0) {
        int k = k0 + q_s * 8;
        int m = bm + m_s;
        if (AMODE == 1) {
            int b = m >> 8, t = m & 255;
            int gh = t >> 3, gw = t & 7;
            int p1 = k >> 4, p2 = k & 15;
            const float* src = &gA[(size_t)b * 65536 + gh * 2048 + p1 * 128 + gw * 16 + p2];
            pa[0] = *(const float4*)src;
            pa[1] = *(const float4*)(src + 4);
        } else if (AMODE == 2) {  // flip-add
            if (m < M && k < K) {
                int b = m / LF, l = m - b * LF;
                const float* s1 = &A[(size_t)m * lda + k];
                const float* s2 = &A2[(size_t)(b * LF + (LF - 1 - l)) * lda + k];
                float4 x0 = *(const float4*)s1, x1 = *(const float4*)(s1 + 4);
                float4 y0 = *(const float4*)s2, y1 = *(const float4*)(s2 + 4);
                pa[0] = make_float4(x0.x + y0.x, x0.y + y0.y, x0.z + y0.z, x0.w + y0.w);
                pa[1] = make_float4(x1.x + y1.x, x1.y + y1.y, x1.z + y1.z, x1.w + y1.w);
            } else { pa[0] = z4; pa[1] = z4; }
        } else {  // AMODE 3: LayerNorm fused; stats from LDS (local row m_s)
            if (m < M && k < K) {
                float2 st = ((const float2*)gA)[m_s];
                float4 r0 = *(const float4*)&A[(size_t)m * lda + k];
                float4 r1 = *(const float4*)&A[(size_t)m * lda + k + 4];
                float4 w0 = *(const float4*)&A2[k],  w1 = *(const float4*)&A2[k + 4];
                float4 b0 = *(const float4*)&pos[k], b1 = *(const float4*)&pos[k + 4];
                pa[0] = make_float4((r0.x - st.x) * st.y * w0.x + b0.x,
                                    (r0.y - st.x) * st.y * w0.y + b0.y,
                                    (r0.z - st.x) * st.y * w0.z + b0.z,
                                    (r0.w - st.x) * st.y * w0.w + b0.w);
                pa[1] = make_float4((r1.x - st.x) * st.y * w1.x + b1.x,
                                    (r1.y - st.x) * st.y * w1.y + b1.y,
                                    (r1.z - st.x) * st.y * w1.z + b1.z,
                                    (r1.w - st.x) * st.y * w1.w + b1.w);
            } else { pa[0] = z4; pa[1] = z4; }
        }
    };
    auto loadW = [&](int k0) {
        int k = k0 + q_s * 8;
        int n = bn + m_s;
        if (n < N && k < K) {
            pw[0] = *(const float4*)&W[(size_t)n * K + k];
            pw[1] = *(const float4*)&W[(size_t)n * K + k + 4];
        } else { pw[0] = z4; pw[1] = z4; }
    };
    auto cvt8 = [&](float4 a, float4 b) -> short8 {
        short8 r;
        r[0] = f2bf(a.x); r[1] = f2bf(a.y); r[2] = f2bf(a.z); r[3] = f2bf(a.w);
        r[4] = f2bf(b.x); r[5] = f2bf(b.y); r[6] = f2bf(b.z); r[7] = f2bf(b.w);
        return r;
    };

    loadA(kb);
    loadW(kb);

    int s = 0;
    for (int k0 = kb; k0 < ke; k0 += 32, ++s) {
        const int buf = (s & 1) * 2048;
        *(short8*)&Ab[buf + (q_s * 64 + m_s) * 8] = cvt8(pa[0], pa[1]);
        *(short8*)&Wb[buf + (q_s * 64 + m_s) * 8] = cvt8(pw[0], pw[1]);
        __syncthreads();
        if (k0 + 32 < ke) { loadA(k0 + 32); loadW(k0 + 32); }
        short8 af0 = *(const short8*)&Ab[buf + (qq * 64 + wm + lr) * 8];
        short8 af1 = *(const short8*)&Ab[buf + (qq * 64 + wm + 16 + lr) * 8];
        short8 wf0 = *(const short8*)&Wb[buf + (qq * 64 + wn + lr) * 8];
        short8 wf1 = *(const short8*)&Wb[buf + (qq * 64 + wn + 16 + lr) * 8];
        acc[0][0] = __builtin_amdgcn_mfma_f32_16x16x32_bf16(af0, wf0, acc[0][0], 0, 0, 0);
        acc[0][1] = __builtin_amdgcn_mfma_f32_16x16x32_bf16(af0, wf1, acc[0][1], 0, 0, 0);
        acc[1][0] = __builtin_amdgcn_mfma_f32_16x16x32_bf16(af1, wf0, acc[1][0], 0, 0, 0);
        acc[1][1] = __builtin_amdgcn_mfma_f32_16x16x32_bf16(af1, wf1, acc[1][1], 0, 0, 0);
    }

    #pragma unroll
    for (int mi = 0; mi < 2; ++mi) {
        #pragma unroll
        for (int ni = 0; ni < 2; ++ni) {
            int col = bn + wn + ni * 16 + lr;
            if (col >= N) continue;
            #pragma unroll
            for (int r = 0; r < 4; ++r) {
                int row = bm + wm + mi * 16 + qq * 4 + r;
                if (row >= M) continue;
                float v = acc[mi][ni][r];
                if (SMODE == 0) {
                    if (bias) v += bias[col];
                    Cout[(size_t)row * N + col] = v;
                } else if (SMODE == 3) {
                    int b = row >> 8, t = row & 255;
                    int l = (t < POSROW) ? t : t + 1;
                    v += bias[col] + pos[(size_t)l * DMODEL + col];
                    Cout[(size_t)(b * LF + l) * DMODEL + col] = v;
                } else {  // SMODE 4
                    atomicAdd(&Cout[(size_t)row * N + col], v);
                }
            }
        }
    }
    __syncthreads();
}

// ---------------------------------------------------------------------------
// patchify (96 tiles) + cls row (block 96)
// ---------------------------------------------------------------------------
__global__ __launch_bounds__(256) void patch_k(MP p) {
    __shared__ __align__(16) short Ab[4096];
    __shared__ __align__(16) short Wb[4096];
    int u = blockIdx.x;
    if (u < 96) {
        int bx = u & 15, by = u >> 4;
        gemm_tile<1, 3>(nullptr, 0, p.patch_w, p.patch_b, p.residual,
                        1024, DMODEL, 256, 0, 256, bx * 64, by * 64,
                        p.depth_seq, nullptr, p.pos_embed, Ab, Wb);
    } else {
        for (int idx = threadIdx.x; idx < BB * DMODEL; idx += 256) {
            int b = idx / DMODEL, t = idx - b * DMODEL;
            p.residual[(size_t)(b * LF + POSROW) * DMODEL + t] =
                p.cls_token[t] + p.pos_embed[(size_t)POSROW * DMODEL + t];
        }
    }
}

// ---------------------------------------------------------------------------
// in_proj with in-kernel LN stats (each block computes its 64 rows' mean/rstd)
// grid: 408 blocks (17 m-tiles x 24 n-tiles)
// ---------------------------------------------------------------------------
__global__ __launch_bounds__(256) void ip_k(MP p, int i) {
    __shared__ __align__(16) short Ab[4096];
    __shared__ __align__(16) short Wb[4096];
    __shared__ float sstat[128];
    const int u = blockIdx.x;
    const int bx = u % 17, ny = u / 17;
    const int bm = bx * 64;
    const int tid = threadIdx.x;
    const int row = bm + (tid >> 2), q = tid & 3;
    float s = 0.f, sq = 0.f;
    if (row < MROWS) {
        const float* x = p.residual + (size_t)row * DMODEL + q * 96;
        #pragma unroll
        for (int k = 0; k < 96; k += 4) {
            float4 v = *(const float4*)&x[k];
            s  += v.x + v.y + v.z + v.w;
            sq += v.x * v.x + v.y * v.y + v.z * v.z + v.w * v.w;
        }
    }
    s  += __shfl_xor(s, 1);  s  += __shfl_xor(s, 2);
    sq += __shfl_xor(sq, 1); sq += __shfl_xor(sq, 2);
    if (q == 0) {
        float mean = s * (1.f / 384.f);
        float var = sq * (1.f / 384.f) - mean * mean;
        sstat[(tid >> 2) * 2]     = mean;
        sstat[(tid >> 2) * 2 + 1] = rsqrtf(var + 1e-5f);
    }
    __syncthreads();
    gemm_tile<3, 0>(p.residual, DMODEL, p.in_proj_w + (size_t)i * 2 * DIN * DMODEL,
                    nullptr, p.xz, MROWS, 2 * DIN, DMODEL, 0, DMODEL, bm, ny * 64,
                    (const float*)sstat, p.ln_w + (size_t)i * DMODEL,
                    p.ln_b + (size_t)i * DMODEL, Ab, Wb);
}

// ---------------------------------------------------------------------------
// Fused conv(K=4)+SiLU -> xproj MFMA tile (one N-tile).
// grid (17 m-tiles, 8 k-chunks, 2 branch); atomic split-K into xdb.
// ---------------------------------------------------------------------------
__global__ __launch_bounds__(256) void xp_k(MP p, int i) {
    __shared__ __align__(16) short Ash[4096];
    __shared__ __align__(16) short Wsh[4096];
    const int br = blockIdx.z;
    const float* cw  = (br ? p.conv_wb : p.conv_w) + (size_t)i * DIN * 4;
    const float* cbv = (br ? p.conv_bb : p.conv_b) + (size_t)i * DIN;
    const float* W   = (br ? p.xproj_wb : p.xproj_w) + (size_t)i * XDB * DIN;
    float* xco       = br ? p.xcb : p.xcf;
    float* xdo       = br ? p.xdbb : p.xdbf;
    const float* xz  = p.xz;

    const int tid = threadIdx.x;
    const int m_s = tid >> 2, q_s = tid & 3;
    const int bm = blockIdx.x * 64;
    const int kb = blockIdx.y * 96;
    const int lane = tid & 63, wv = tid >> 6;
    const int wm = (wv >> 1) * 32, wn = (wv & 1) * 32;
    const int qq = lane >> 4, lr = lane & 15;
    const int m = bm + m_s;
    const bool mok = (m < MROWS);
    int b = 0, l = 0;
    if (mok) { b = m / LF; l = m - b * LF; }

    f32x4 acc[2][2];
    #pragma unroll
    for (int i2 = 0; i2 < 2; ++i2)
        #pragma unroll
        for (int j = 0; j < 2; ++j)
            acc[i2][j] = f32x4{0.f, 0.f, 0.f, 0.f};

    float a8[8];
    float4 pw0, pw1;
    const float4 z4 = make_float4(0.f, 0.f, 0.f, 0.f);

    auto loadA = [&](int k0) {
        int d0 = k0 + q_s * 8;
        if (mok) {
            float4 c0 = *(const float4*)&cbv[d0];
            float4 c1 = *(const float4*)&cbv[d0 + 4];
            a8[0] = c0.x; a8[1] = c0.y; a8[2] = c0.z; a8[3] = c0.w;
            a8[4] = c1.x; a8[5] = c1.y; a8[6] = c1.z; a8[7] = c1.w;
            float wreg[8][4];
            #pragma unroll
            for (int j = 0; j < 8; ++j)
                *(float4*)wreg[j] = *(const float4*)&cw[(d0 + j) * 4];
            #pragma unroll
            for (int kk = 0; kk < 4; ++kk) {
                int li = l - 3 + kk;
                if (li >= 0) {
                    int srow = br ? (b * LF + (LF - 1 - li)) : (b * LF + li);
                    const float* xp = &xz[(size_t)srow * 2 * DIN + d0];
                    float4 x0 = *(const float4*)xp, x1 = *(const float4*)(xp + 4);
                    a8[0] += x0.x * wreg[0][kk]; a8[1] += x0.y * wreg[1][kk];
                    a8[2] += x0.z * wreg[2][kk]; a8[3] += x0.w * wreg[3][kk];
                    a8[4] += x1.x * wreg[4][kk]; a8[5] += x1.y * wreg[5][kk];
                    a8[6] += x1.z * wreg[6][kk]; a8[7] += x1.w * wreg[7][kk];
                }
            }
            #pragma unroll
            for (int j = 0; j < 8; ++j) a8[j] = siluf(a8[j]);
        } else {
            #pragma unroll
            for (int j = 0; j < 8; ++j) a8[j] = 0.f;
        }
    };
    auto loadW = [&](int k0) {
        int k = k0 + q_s * 8;
        if (m_s < XDB) {
            pw0 = *(const float4*)&W[(size_t)m_s * DIN + k];
            pw1 = *(const float4*)&W[(size_t)m_s * DIN + k + 4];
        } else { pw0 = z4; pw1 = z4; }
    };
    auto cvt8f = [&]() -> short8 {
        short8 r;
        #pragma unroll
        for (int j = 0; j < 8; ++j) r[j] = f2bf(a8[j]);
        return r;
    };
    auto cvt8w = [&]() -> short8 {
        short8 r;
        r[0] = f2bf(pw0.x); r[1] = f2bf(pw0.y); r[2] = f2bf(pw0.z); r[3] = f2bf(pw0.w);
        r[4] = f2bf(pw1.x); r[5] = f2bf(pw1.y); r[6] = f2bf(pw1.z); r[7] = f2bf(pw1.w);
        return r;
    };

    loadA(kb);
    loadW(kb);

    #pragma unroll
    for (int s = 0; s < 3; ++s) {
        const int k0 = kb + s * 32;
        const int buf = (s & 1) * 2048;
        *(short8*)&Ash[buf + (q_s * 64 + m_s) * 8] = cvt8f();
        *(short8*)&Wsh[buf + (q_s * 64 + m_s) * 8] = cvt8w();
        if (mok) {
            int d0 = k0 + q_s * 8;
            *(float4*)&xco[(size_t)m * DIN + d0] =
                make_float4(a8[0], a8[1], a8[2], a8[3]);
            *(float4*)&xco[(size_t)m * DIN + d0 + 4] =
                make_float4(a8[4], a8[5], a8[6], a8[7]);
        }
        __syncthreads();
        if (s + 1 < 3) { loadA(k0 + 32); loadW(k0 + 32); }
        short8 af0 = *(const short8*)&Ash[buf + (qq * 64 + wm + lr) * 8];
        short8 af1 = *(const short8*)&Ash[buf + (qq * 64 + wm + 16 + lr) * 8];
        short8 wf0 = *(const short8*)&Wsh[buf + (qq * 64 + wn + lr) * 8];
        short8 wf1 = *(const short8*)&Wsh[buf + (qq * 64 + wn + 16 + lr) * 8];
        acc[0][0] = __builtin_amdgcn_mfma_f32_16x16x32_bf16(af0, wf0, acc[0][0], 0, 0, 0);
        acc[0][1] = __builtin_amdgcn_mfma_f32_16x16x32_bf16(af0, wf1, acc[0][1], 0, 0, 0);
        acc[1][0] = __builtin_amdgcn_mfma_f32_16x16x32_bf16(af1, wf0, acc[1][0], 0, 0, 0);
        acc[1][1] = __builtin_amdgcn_mfma_f32_16x16x32_bf16(af1, wf1, acc[1][1], 0, 0, 0);
        if (s + 1 < 3) __syncthreads();
    }

    #pragma unroll
    for (int mi = 0; mi < 2; ++mi) {
        #pragma unroll
        for (int ni = 0; ni < 2; ++ni) {
            int col = wn + ni * 16 + lr;
            if (col >= XDB) continue;
            #pragma unroll
            for (int r = 0; r < 4; ++r) {
                int row = bm + wm + mi * 16 + qq * 4 + r;
                if (row >= MROWS) continue;
                atomicAdd(&xdo[(size_t)row * XDB + col], acc[mi][ni][r]);
            }
        }
    }
}

// ---------------------------------------------------------------------------
// Single-pass chunked scan with decoupled lookback + fused dt-projection.
// grid (51, 8): u=blockIdx.x -> dx=u/17, c=u%17 (c=0 blocks dispatch early);
// y=blockIdx.y = b*2+br. Publishes (hpart, sumd) + release flag; lookback
// accumulates prefix h_in = sum_j (prod_k E_k) hp_j; reruns recurrence with
// dt/xc/zv held in registers.
// ---------------------------------------------------------------------------
__global__ __launch_bounds__(256) void scan1_k(MP p, int i) {
    __shared__ float sXD[CL * DTR];
    __shared__ float sB[CL * NST];
    __shared__ float sC[CL * NST];
    const int t = threadIdx.x;
    const int u = blockIdx.x;
    const int dx = u / 17, c = u % 17;
    const int y = blockIdx.y;
    const int b = y >> 1, br = y & 1;
    const int d = dx * 256 + t;
    const float* xc  = br ? p.xcb : p.xcf;
    const float* xdb = br ? p.xdbb : p.xdbf;
    const float* Al  = (br ? p.A_logb : p.A_log) + (size_t)i * DIN * NST;
    const float* Dpp = (br ? p.Dpb : p.Dp) + (size_t)i * DIN;
    const float* dw  = (br ? p.dtproj_wb : p.dtproj_w) + (size_t)i * DIN * DTR;
    const float* dbi = (br ? p.dtproj_bb : p.dtproj_b) + (size_t)i * DIN;
    float* yo = br ? p.ybb : p.yfb;

    float An[NST];
    #pragma unroll
    for (int n = 0; n < NST; ++n) An[n] = -__expf(Al[(size_t)d * NST + n]);
    float wdt[DTR];
    #pragma unroll
    for (int k = 0; k < DTR; k += 4)
        *(float4*)&wdt[k] = *(const float4*)&dw[(size_t)d * DTR + k];
    const float dbv = dbi[d];
    const float Dv = Dpp[d];

    for (int idx = t; idx < CL * DTR; idx += 256) {
        int s0 = idx / DTR, j0 = idx - s0 * DTR;
        int l0 = c * CL + s0;
        sXD[s0 * DTR + j0] = (l0 < LF) ? xdb[(size_t)(b * LF + l0) * XDB + j0] : 0.f;
    }
    {
        int s0 = t >> 4, j0 = t & 15;
        int l0 = c * CL + s0;
        size_t rb = (size_t)(b * LF + l0) * XDB + DTR;
        sB[s0 * NST + j0] = (l0 < LF) ? xdb[rb + j0] : 0.f;
        sC[s0 * NST + j0] = (l0 < LF) ? xdb[rb + NST + j0] : 0.f;
    }
    __syncthreads();

    // register-held inputs
    float xv[CL], dc[CL];
    #pragma unroll
    for (int s = 0; s < CL; ++s) {
        int l = c * CL + s;
        xv[s] = (l < LF) ? xc[(size_t)(b * LF + l) * DIN + d] : 0.f;
    }
    #pragma unroll
    for (int s = 0; s < CL; ++s) {
        float dtv = dbv;
        #pragma unroll
        for (int k = 0; k < DTR; ++k) dtv += sXD[s * DTR + k] * wdt[k];
        dc[s] = softplusf(dtv);
    }

    // local pass
    float h[NST] = {};
    float sdt = 0.f;
    #pragma unroll
    for (int s = 0; s < CL; ++s) {
        int l = c * CL + s;
        if (l < LF) {
            sdt += dc[s];
            float dtx = dc[s] * xv[s];
            #pragma unroll
            for (int n = 0; n < NST; ++n)
                h[n] = __expf(dc[s] * An[n]) * h[n] + dtx * sB[s * NST + n];
        }
    }
    // publish partials + release flag
    {
        size_t base = (size_t)(c * 8 + y) * NST;
        #pragma unroll
        for (int n = 0; n < NST; ++n) p.hpart[(base + n) * DIN + d] = h[n];
        p.sumd[(size_t)(c * 8 + y) * DIN + d] = sdt;
    }
    __syncthreads();   // compiler drains vmcnt before barrier -> stores done
    if (t == 0) {
        __threadfence();
        atomicExch(&p.flags[(c * 8 + y) * 3 + dx], 1);
    }

    // prefetch z gate values (in flight during lookback)
    float zv[CL];
    #pragma unroll
    for (int s = 0; s < CL; ++s) {
        int l = c * CL + s;
        int zl = br ? (LF - 1 - l) : l;
        zv[s] = (l < LF) ? p.xz[(size_t)(b * LF + zl) * (2 * DIN) + DIN + d] : 0.f;
    }

    // lookback: h_in = hp_{c-1} + E_{c-1} hp_{c-2} + ...
    float hi[NST] = {};
    float P[NST];
    #pragma unroll
    for (int n = 0; n < NST; ++n) P[n] = 1.f;
    for (int j = c - 1; j >= 0; --j) {
        if (t == 0) {
            while (atomicAdd(&p.flags[(j * 8 + y) * 3 + dx], 0) == 0) {}
        }
        __syncthreads();
        __threadfence();
        float sdj = p.sumd[(size_t)(j * 8 + y) * DIN + d];
        size_t bj = (size_t)(j * 8 + y) * NST;
        #pragma unroll
        for (int n = 0; n < NST; ++n) {
            float hp = p.hpart[(bj + n) * DIN + d];
            hi[n] += P[n] * hp;
            P[n] *= __expf(An[n] * sdj);
        }
    }

    // final pass with correct h_in
    #pragma unroll
    for (int n = 0; n < NST; ++n) h[n] = hi[n];
    #pragma unroll
    for (int s = 0; s < CL; ++s) {
        int l = c * CL + s;
        if (l < LF) {
            float dtx = dc[s] * xv[s];
            float acc = 0.f;
            #pragma unroll
            for (int n = 0; n < NST; ++n) {
                h[n] = __expf(dc[s] * An[n]) * h[n] + dtx * sB[s * NST + n];
                acc += h[n] * sC[s * NST + n];
            }
            yo[(size_t)(b * LF + l) * DIN + d] = (acc + xv[s] * Dv) * siluf(zv[s]);
        }
    }
}

// ---------------------------------------------------------------------------
// out_proj standalone wrapper (flip-add A, split-K atomics into residual)
// ---------------------------------------------------------------------------
template<int AMODE, int SMODE>
__global__ __launch_bounds__(256) void mgemm_k(
    const float* A, int lda, const float* W, const float* bias,
    float* Cout, int M, int N, int K, int KS,
    const float* gA, const float* A2, const float* pos)
{
    __shared__ __align__(16) short Ab[4096];
    __shared__ __align__(16) short Wb[4096];
    int ntile = blockIdx.y / KS, ks = blockIdx.y % KS;
    int chunk = K / KS;
    gemm_tile<AMODE, SMODE>(A, lda, W, bias, Cout, M, N, K,
                            ks * chunk, ks * chunk + chunk,
                            blockIdx.x * 64, ntile * 64, gA, A2, pos, Ab, Wb);
}

// final LN(row POS) + command MLP + add, 256 threads
__global__ __launch_bounds__(256) void final_k(MP p) {
    __shared__ float sm[416];
    float* hid   = sm;
    float* cmdin = sm + 384;
    float* red   = sm + 404;
    int b = blockIdx.x, t = threadIdx.x;
    const float* x = p.residual + (size_t)(b * LF + POSROW) * DMODEL;
    float v0 = x[t];
    float v1 = (t < 128) ? x[t + 256] : 0.f;
    float s = v0 + v1, sq = v0 * v0 + v1 * v1;
    #pragma unroll
    for (int o = 32; o > 0; o >>= 1) {
        s += __shfl_down(s, o);
        sq += __shfl_down(sq, o);
    }
    if ((t & 63) == 0) { red[t >> 6] = s; red[4 + (t >> 6)] = sq; }
    if (t < 20) cmdin[t] = (t < 16) ? p.state_vec[b * 16 + t] : p.action[b * 4 + t - 16];
    __syncthreads();
    float S = red[0] + red[1] + red[2] + red[3];
    float Q = red[4] + red[5] + red[6] + red[7];
    float mean = S * (1.f / 384.f);
    float var = Q * (1.f / 384.f) - mean * mean;
    float rs = rsqrtf(var + 1e-5f);
    {
        float a1 = p.cb1[t];
        #pragma unroll
        for (int k = 0; k < 20; ++k) a1 += cmdin[k] * p.cw1[t * 20 + k];
        hid[t] = fmaxf(a1, 0.f);
        if (t < 128) {
            int j = t + 256;
            float a1b = p.cb1[j];
            #pragma unroll
            for (int k = 0; k < 20; ++k) a1b += cmdin[k] * p.cw1[j * 20 + k];
            hid[j] = fmaxf(a1b, 0.f);
        }
    }
    __syncthreads();
    {
        float a2 = p.cb2[t];
        for (int k = 0; k < DMODEL; ++k) a2 += hid[k] * p.cw2[t * DMODEL + k];
        float vis = (v0 - mean) * rs * p.lnf_w[t] + p.lnf_b[t];
        p.out[b * DMODEL + t] = vis + a2;
        if (t < 128) {
            int j = t + 256;
            float a2b = p.cb2[j];
            for (int k = 0; k < DMODEL; ++k) a2b += hid[k] * p.cw2[j * DMODEL + k];
            float visb = (v1 - mean) * rs * p.lnf_w[j] + p.lnf_b[j];
            p.out[b * DMODEL + j] = visb + a2b;
        }
    }
}

extern "C" void kernel_launch(void* const* d_in, const int* in_sizes, int n_in,
                              void* d_out, int out_size, void* d_ws, size_t ws_size,
                              hipStream_t stream) {
    MP p;
    p.depth_seq = (const float*)d_in[0];
    p.state_vec = (const float*)d_in[1];
    p.action    = (const float*)d_in[2];
    p.patch_w   = (const float*)d_in[3];
    p.patch_b   = (const float*)d_in[4];
    p.cls_token = (const float*)d_in[5];
    p.pos_embed = (const float*)d_in[6];
    p.ln_w      = (const float*)d_in[7];
    p.ln_b      = (const float*)d_in[8];
    p.in_proj_w = (const float*)d_in[9];
    p.conv_w    = (const float*)d_in[10];
    p.conv_b    = (const float*)d_in[11];
    p.conv_wb   = (const float*)d_in[12];
    p.conv_bb   = (const float*)d_in[13];
    p.xproj_w   = (const float*)d_in[14];
    p.xproj_wb  = (const float*)d_in[15];
    p.dtproj_w  = (const float*)d_in[16];
    p.dtproj_b  = (const float*)d_in[17];
    p.dtproj_wb = (const float*)d_in[18];
    p.dtproj_bb = (const float*)d_in[19];
    p.A_log     = (const float*)d_in[20];
    p.A_logb    = (const float*)d_in[21];
    p.Dp        = (const float*)d_in[22];
    p.Dpb       = (const float*)d_in[23];
    p.out_w     = (const float*)d_in[24];
    p.lnf_w     = (const float*)d_in[25];
    p.lnf_b     = (const float*)d_in[26];
    p.cw1       = (const float*)d_in[27];
    p.cb1       = (const float*)d_in[28];
    p.cw2       = (const float*)d_in[29];
    p.cb2       = (const float*)d_in[30];

    float* ws = (float*)d_ws;
    size_t o = 0;
    p.residual = ws + o; o += (size_t)MROWS * DMODEL;
    p.xz       = ws + o; o += (size_t)MROWS * 2 * DIN;
    p.xcf      = ws + o; o += (size_t)MROWS * DIN;
    p.xcb      = ws + o; o += (size_t)MROWS * DIN;
    p.xdbf     = ws + o; o += (size_t)MROWS * XDB;
    p.xdbb     = ws + o; o += (size_t)MROWS * XDB;
    p.flags    = (int*)(ws + o); o += 408;
    p.yfb      = ws + o; o += (size_t)MROWS * DIN;
    p.ybb      = ws + o; o += (size_t)MROWS * DIN;
    p.hpart    = ws + o; o += (size_t)NC * 8 * NST * DIN;
    p.sumd     = ws + o; o += (size_t)NC * 8 * DIN;
    p.out      = (float*)d_out;
    (void)ws_size; (void)in_sizes; (void)n_in; (void)out_size;

    patch_k<<<97, 256, 0, stream>>>(p);

    for (int i = 0; i < 4; ++i) {
        ip_k<<<408, 256, 0, stream>>>(p, i);
        // zero xdbf + xdbb + flags (contiguous)
        hipMemsetAsync(p.xdbf, 0, ((size_t)2 * MROWS * XDB + 408) * 4, stream);
        xp_k<<<dim3(17, 8, 2), 256, 0, stream>>>(p, i);
        scan1_k<<<dim3(51, 8), 256, 0, stream>>>(p, i);
        mgemm_k<2, 4><<<dim3(17, 24), 256, 0, stream>>>(
            p.yfb, DIN, p.out_w + (size_t)i * DMODEL * DIN, nullptr,
            p.residual, MROWS, DMODEL, DIN, 4, nullptr, p.ybb, nullptr);
    }

    final_k<<<BB, 256, 0, stream>>>(p);
}

// Round 13
// 655.942 us; speedup vs baseline: 2.8040x; 2.8040x over previous
//
#include <hip/hip_runtime.h>
#include <math.h>

#define BB 4
#define LF 257      // NTOK+1
#define DMODEL 384
#define DIN 768
#define NST 16
#define DTR 24
#define XDB 56      // DTR + 2*N
#define POSROW 128
#define CL 16       // scan chunk length
#define NC 17       // ceil(LF/CL)
#define MROWS (BB * LF)   // 1028

typedef __attribute__((ext_vector_type(8))) short short8;
typedef __attribute__((ext_vector_type(4))) float f32x4;

__device__ __forceinline__ float siluf(float v) { return v / (1.f + __expf(-v)); }
__device__ __forceinline__ float softplusf(float v) {
    return (v > 20.f) ? v : log1pf(__expf(v));
}
__device__ __forceinline__ short f2bf(float f) {
    unsigned u = __builtin_bit_cast(unsigned, f);
    unsigned r = (u + 0x7FFFu + ((u >> 16) & 1u)) >> 16;
    return (short)r;
}

struct MP {
    const float *depth_seq, *state_vec, *action, *patch_w, *patch_b;
    const float *cls_token, *pos_embed;
    const float *ln_w, *ln_b, *in_proj_w, *conv_w, *conv_b, *conv_wb, *conv_bb;
    const float *xproj_w, *xproj_wb, *dtproj_w, *dtproj_b, *dtproj_wb, *dtproj_bb;
    const float *A_log, *A_logb, *Dp, *Dpb, *out_w, *lnf_w, *lnf_b;
    const float *cw1, *cb1, *cw2, *cb2;
    float *residual, *xz, *xcf, *xcb, *xdbf, *xdbb, *yfb, *ybb, *hpart, *sumd;
    float* out;
};

// ---------------------------------------------------------------------------
// bf16-MFMA 64x64 GEMM tile over K range [kb,ke). 4 waves (2x2), each wave
// 2x2 mfma_f32_16x16x32_bf16. f32 global -> RNE bf16 -> LDS fragment order.
// AMODE: 1 patch gather, 2 flip-add, 3 LN-fused (gA = LDS stats[64]{mean,rstd},
//        A2=lnw, pos=lnb).  SMODE: 0 plain(+bias), 3 patchify store, 4 atomicAdd
// ---------------------------------------------------------------------------
template<int AMODE, int SMODE>
__device__ void gemm_tile(
    const float* __restrict__ A, int lda,
    const float* __restrict__ W,
    const float* __restrict__ bias,
    float* __restrict__ Cout, int M, int N, int K, int kb, int ke,
    int bm, int bn,
    const float* __restrict__ gA, const float* __restrict__ A2,
    const float* __restrict__ pos,
    short* __restrict__ Ab, short* __restrict__ Wb)
{
    const int tid = threadIdx.x;
    const int m_s = tid >> 2;
    const int q_s = tid & 3;
    const int lane = tid & 63;
    const int wv = tid >> 6;
    const int wm = (wv >> 1) * 32, wn = (wv & 1) * 32;
    const int qq = lane >> 4, lr = lane & 15;

    f32x4 acc[2][2];
    #pragma unroll
    for (int i = 0; i < 2; ++i)
        #pragma unroll
        for (int j = 0; j < 2; ++j)
            acc[i][j] = f32x4{0.f, 0.f, 0.f, 0.f};

    float4 pa[2], pw[2];
    const float4 z4 = make_float4(0.f, 0.f, 0.f, 0.f);

    auto loadA = [&](int k0) {
        int k = k0 + q_s * 8;
        int m = bm + m_s;
        if (AMODE == 1) {
            int b = m >> 8, t = m & 255;
            int gh = t >> 3, gw = t & 7;
            int p1 = k >> 4, p2 = k & 15;
            const float* src = &gA[(size_t)b * 65536 + gh * 2048 + p1 * 128 + gw * 16 + p2];
            pa[0] = *(const float4*)src;
            pa[1] = *(const float4*)(src + 4);
        } else if (AMODE == 2) {  // flip-add
            if (m < M && k < K) {
                int b = m / LF, l = m - b * LF;
                const float* s1 = &A[(size_t)m * lda + k];
                const float* s2 = &A2[(size_t)(b * LF + (LF - 1 - l)) * lda + k];
                float4 x0 = *(const float4*)s1, x1 = *(const float4*)(s1 + 4);
                float4 y0 = *(const float4*)s2, y1 = *(const float4*)(s2 + 4);
                pa[0] = make_float4(x0.x + y0.x, x0.y + y0.y, x0.z + y0.z, x0.w + y0.w);
                pa[1] = make_float4(x1.x + y1.x, x1.y + y1.y, x1.z + y1.z, x1.w + y1.w);
            } else { pa[0] = z4; pa[1] = z4; }
        } else {  // AMODE 3: LayerNorm fused; stats from LDS (local row m_s)
            if (m < M && k < K) {
                float2 st = ((const float2*)gA)[m_s];
                float4 r0 = *(const float4*)&A[(size_t)m * lda + k];
                float4 r1 = *(const float4*)&A[(size_t)m * lda + k + 4];
                float4 w0 = *(const float4*)&A2[k],  w1 = *(const float4*)&A2[k + 4];
                float4 b0 = *(const float4*)&pos[k], b1 = *(const float4*)&pos[k + 4];
                pa[0] = make_float4((r0.x - st.x) * st.y * w0.x + b0.x,
                                    (r0.y - st.x) * st.y * w0.y + b0.y,
                                    (r0.z - st.x) * st.y * w0.z + b0.z,
                                    (r0.w - st.x) * st.y * w0.w + b0.w);
                pa[1] = make_float4((r1.x - st.x) * st.y * w1.x + b1.x,
                                    (r1.y - st.x) * st.y * w1.y + b1.y,
                                    (r1.z - st.x) * st.y * w1.z + b1.z,
                                    (r1.w - st.x) * st.y * w1.w + b1.w);
            } else { pa[0] = z4; pa[1] = z4; }
        }
    };
    auto loadW = [&](int k0) {
        int k = k0 + q_s * 8;
        int n = bn + m_s;
        if (n < N && k < K) {
            pw[0] = *(const float4*)&W[(size_t)n * K + k];
            pw[1] = *(const float4*)&W[(size_t)n * K + k + 4];
        } else { pw[0] = z4; pw[1] = z4; }
    };
    auto cvt8 = [&](float4 a, float4 b) -> short8 {
        short8 r;
        r[0] = f2bf(a.x); r[1] = f2bf(a.y); r[2] = f2bf(a.z); r[3] = f2bf(a.w);
        r[4] = f2bf(b.x); r[5] = f2bf(b.y); r[6] = f2bf(b.z); r[7] = f2bf(b.w);
        return r;
    };

    loadA(kb);
    loadW(kb);

    int s = 0;
    for (int k0 = kb; k0 < ke; k0 += 32, ++s) {
        const int buf = (s & 1) * 2048;
        *(short8*)&Ab[buf + (q_s * 64 + m_s) * 8] = cvt8(pa[0], pa[1]);
        *(short8*)&Wb[buf + (q_s * 64 + m_s) * 8] = cvt8(pw[0], pw[1]);
        __syncthreads();
        if (k0 + 32 < ke) { loadA(k0 + 32); loadW(k0 + 32); }
        short8 af0 = *(const short8*)&Ab[buf + (qq * 64 + wm + lr) * 8];
        short8 af1 = *(const short8*)&Ab[buf + (qq * 64 + wm + 16 + lr) * 8];
        short8 wf0 = *(const short8*)&Wb[buf + (qq * 64 + wn + lr) * 8];
        short8 wf1 = *(const short8*)&Wb[buf + (qq * 64 + wn + 16 + lr) * 8];
        acc[0][0] = __builtin_amdgcn_mfma_f32_16x16x32_bf16(af0, wf0, acc[0][0], 0, 0, 0);
        acc[0][1] = __builtin_amdgcn_mfma_f32_16x16x32_bf16(af0, wf1, acc[0][1], 0, 0, 0);
        acc[1][0] = __builtin_amdgcn_mfma_f32_16x16x32_bf16(af1, wf0, acc[1][0], 0, 0, 0);
        acc[1][1] = __builtin_amdgcn_mfma_f32_16x16x32_bf16(af1, wf1, acc[1][1], 0, 0, 0);
    }

    #pragma unroll
    for (int mi = 0; mi < 2; ++mi) {
        #pragma unroll
        for (int ni = 0; ni < 2; ++ni) {
            int col = bn + wn + ni * 16 + lr;
            if (col >= N) continue;
            #pragma unroll
            for (int r = 0; r < 4; ++r) {
                int row = bm + wm + mi * 16 + qq * 4 + r;
                if (row >= M) continue;
                float v = acc[mi][ni][r];
                if (SMODE == 0) {
                    if (bias) v += bias[col];
                    Cout[(size_t)row * N + col] = v;
                } else if (SMODE == 3) {
                    int b = row >> 8, t = row & 255;
                    int l = (t < POSROW) ? t : t + 1;
                    v += bias[col] + pos[(size_t)l * DMODEL + col];
                    Cout[(size_t)(b * LF + l) * DMODEL + col] = v;
                } else {  // SMODE 4
                    atomicAdd(&Cout[(size_t)row * N + col], v);
                }
            }
        }
    }
    __syncthreads();
}

// ---------------------------------------------------------------------------
// patchify (96 tiles) + cls row (block 96)
// ---------------------------------------------------------------------------
__global__ __launch_bounds__(256) void patch_k(MP p) {
    __shared__ __align__(16) short Ab[4096];
    __shared__ __align__(16) short Wb[4096];
    int u = blockIdx.x;
    if (u < 96) {
        int bx = u & 15, by = u >> 4;
        gemm_tile<1, 3>(nullptr, 0, p.patch_w, p.patch_b, p.residual,
                        1024, DMODEL, 256, 0, 256, bx * 64, by * 64,
                        p.depth_seq, nullptr, p.pos_embed, Ab, Wb);
    } else {
        for (int idx = threadIdx.x; idx < BB * DMODEL; idx += 256) {
            int b = idx / DMODEL, t = idx - b * DMODEL;
            p.residual[(size_t)(b * LF + POSROW) * DMODEL + t] =
                p.cls_token[t] + p.pos_embed[(size_t)POSROW * DMODEL + t];
        }
    }
}

// ---------------------------------------------------------------------------
// in_proj with in-kernel LN stats (each block computes its 64 rows' mean/rstd)
// grid: 408 blocks (17 m-tiles x 24 n-tiles)
// ---------------------------------------------------------------------------
__global__ __launch_bounds__(256) void ip_k(MP p, int i) {
    __shared__ __align__(16) short Ab[4096];
    __shared__ __align__(16) short Wb[4096];
    __shared__ float sstat[128];
    const int u = blockIdx.x;
    const int bx = u % 17, ny = u / 17;
    const int bm = bx * 64;
    const int tid = threadIdx.x;
    const int row = bm + (tid >> 2), q = tid & 3;
    float s = 0.f, sq = 0.f;
    if (row < MROWS) {
        const float* x = p.residual + (size_t)row * DMODEL + q * 96;
        #pragma unroll
        for (int k = 0; k < 96; k += 4) {
            float4 v = *(const float4*)&x[k];
            s  += v.x + v.y + v.z + v.w;
            sq += v.x * v.x + v.y * v.y + v.z * v.z + v.w * v.w;
        }
    }
    s  += __shfl_xor(s, 1);  s  += __shfl_xor(s, 2);
    sq += __shfl_xor(sq, 1); sq += __shfl_xor(sq, 2);
    if (q == 0) {
        float mean = s * (1.f / 384.f);
        float var = sq * (1.f / 384.f) - mean * mean;
        sstat[(tid >> 2) * 2]     = mean;
        sstat[(tid >> 2) * 2 + 1] = rsqrtf(var + 1e-5f);
    }
    __syncthreads();
    gemm_tile<3, 0>(p.residual, DMODEL, p.in_proj_w + (size_t)i * 2 * DIN * DMODEL,
                    nullptr, p.xz, MROWS, 2 * DIN, DMODEL, 0, DMODEL, bm, ny * 64,
                    (const float*)sstat, p.ln_w + (size_t)i * DMODEL,
                    p.ln_b + (size_t)i * DMODEL, Ab, Wb);
}

// ---------------------------------------------------------------------------
// Fused conv(K=4)+SiLU -> xproj MFMA tile (one N-tile).
// grid (17 m-tiles, 8 k-chunks, 2 branch); atomic split-K into xdb.
// ---------------------------------------------------------------------------
__global__ __launch_bounds__(256) void xp_k(MP p, int i) {
    __shared__ __align__(16) short Ash[4096];
    __shared__ __align__(16) short Wsh[4096];
    const int br = blockIdx.z;
    const float* cw  = (br ? p.conv_wb : p.conv_w) + (size_t)i * DIN * 4;
    const float* cbv = (br ? p.conv_bb : p.conv_b) + (size_t)i * DIN;
    const float* W   = (br ? p.xproj_wb : p.xproj_w) + (size_t)i * XDB * DIN;
    float* xco       = br ? p.xcb : p.xcf;
    float* xdo       = br ? p.xdbb : p.xdbf;
    const float* xz  = p.xz;

    const int tid = threadIdx.x;
    const int m_s = tid >> 2, q_s = tid & 3;
    const int bm = blockIdx.x * 64;
    const int kb = blockIdx.y * 96;
    const int lane = tid & 63, wv = tid >> 6;
    const int wm = (wv >> 1) * 32, wn = (wv & 1) * 32;
    const int qq = lane >> 4, lr = lane & 15;
    const int m = bm + m_s;
    const bool mok = (m < MROWS);
    int b = 0, l = 0;
    if (mok) { b = m / LF; l = m - b * LF; }

    f32x4 acc[2][2];
    #pragma unroll
    for (int i2 = 0; i2 < 2; ++i2)
        #pragma unroll
        for (int j = 0; j < 2; ++j)
            acc[i2][j] = f32x4{0.f, 0.f, 0.f, 0.f};

    float a8[8];
    float4 pw0, pw1;
    const float4 z4 = make_float4(0.f, 0.f, 0.f, 0.f);

    auto loadA = [&](int k0) {
        int d0 = k0 + q_s * 8;
        if (mok) {
            float4 c0 = *(const float4*)&cbv[d0];
            float4 c1 = *(const float4*)&cbv[d0 + 4];
            a8[0] = c0.x; a8[1] = c0.y; a8[2] = c0.z; a8[3] = c0.w;
            a8[4] = c1.x; a8[5] = c1.y; a8[6] = c1.z; a8[7] = c1.w;
            float wreg[8][4];
            #pragma unroll
            for (int j = 0; j < 8; ++j)
                *(float4*)wreg[j] = *(const float4*)&cw[(d0 + j) * 4];
            #pragma unroll
            for (int kk = 0; kk < 4; ++kk) {
                int li = l - 3 + kk;
                if (li >= 0) {
                    int srow = br ? (b * LF + (LF - 1 - li)) : (b * LF + li);
                    const float* xp = &xz[(size_t)srow * 2 * DIN + d0];
                    float4 x0 = *(const float4*)xp, x1 = *(const float4*)(xp + 4);
                    a8[0] += x0.x * wreg[0][kk]; a8[1] += x0.y * wreg[1][kk];
                    a8[2] += x0.z * wreg[2][kk]; a8[3] += x0.w * wreg[3][kk];
                    a8[4] += x1.x * wreg[4][kk]; a8[5] += x1.y * wreg[5][kk];
                    a8[6] += x1.z * wreg[6][kk]; a8[7] += x1.w * wreg[7][kk];
                }
            }
            #pragma unroll
            for (int j = 0; j < 8; ++j) a8[j] = siluf(a8[j]);
        } else {
            #pragma unroll
            for (int j = 0; j < 8; ++j) a8[j] = 0.f;
        }
    };
    auto loadW = [&](int k0) {
        int k = k0 + q_s * 8;
        if (m_s < XDB) {
            pw0 = *(const float4*)&W[(size_t)m_s * DIN + k];
            pw1 = *(const float4*)&W[(size_t)m_s * DIN + k + 4];
        } else { pw0 = z4; pw1 = z4; }
    };
    auto cvt8f = [&]() -> short8 {
        short8 r;
        #pragma unroll
        for (int j = 0; j < 8; ++j) r[j] = f2bf(a8[j]);
        return r;
    };
    auto cvt8w = [&]() -> short8 {
        short8 r;
        r[0] = f2bf(pw0.x); r[1] = f2bf(pw0.y); r[2] = f2bf(pw0.z); r[3] = f2bf(pw0.w);
        r[4] = f2bf(pw1.x); r[5] = f2bf(pw1.y); r[6] = f2bf(pw1.z); r[7] = f2bf(pw1.w);
        return r;
    };

    loadA(kb);
    loadW(kb);

    #pragma unroll
    for (int s = 0; s < 3; ++s) {
        const int k0 = kb + s * 32;
        const int buf = (s & 1) * 2048;
        *(short8*)&Ash[buf + (q_s * 64 + m_s) * 8] = cvt8f();
        *(short8*)&Wsh[buf + (q_s * 64 + m_s) * 8] = cvt8w();
        if (mok) {
            int d0 = k0 + q_s * 8;
            *(float4*)&xco[(size_t)m * DIN + d0] =
                make_float4(a8[0], a8[1], a8[2], a8[3]);
            *(float4*)&xco[(size_t)m * DIN + d0 + 4] =
                make_float4(a8[4], a8[5], a8[6], a8[7]);
        }
        __syncthreads();
        if (s + 1 < 3) { loadA(k0 + 32); loadW(k0 + 32); }
        short8 af0 = *(const short8*)&Ash[buf + (qq * 64 + wm + lr) * 8];
        short8 af1 = *(const short8*)&Ash[buf + (qq * 64 + wm + 16 + lr) * 8];
        short8 wf0 = *(const short8*)&Wsh[buf + (qq * 64 + wn + lr) * 8];
        short8 wf1 = *(const short8*)&Wsh[buf + (qq * 64 + wn + 16 + lr) * 8];
        acc[0][0] = __builtin_amdgcn_mfma_f32_16x16x32_bf16(af0, wf0, acc[0][0], 0, 0, 0);
        acc[0][1] = __builtin_amdgcn_mfma_f32_16x16x32_bf16(af0, wf1, acc[0][1], 0, 0, 0);
        acc[1][0] = __builtin_amdgcn_mfma_f32_16x16x32_bf16(af1, wf0, acc[1][0], 0, 0, 0);
        acc[1][1] = __builtin_amdgcn_mfma_f32_16x16x32_bf16(af1, wf1, acc[1][1], 0, 0, 0);
        if (s + 1 < 3) __syncthreads();
    }

    #pragma unroll
    for (int mi = 0; mi < 2; ++mi) {
        #pragma unroll
        for (int ni = 0; ni < 2; ++ni) {
            int col = wn + ni * 16 + lr;
            if (col >= XDB) continue;
            #pragma unroll
            for (int r = 0; r < 4; ++r) {
                int row = bm + wm + mi * 16 + qq * 4 + r;
                if (row >= MROWS) continue;
                atomicAdd(&xdo[(size_t)row * XDB + col], acc[mi][ni][r]);
            }
        }
    }
}

// ---------------------------------------------------------------------------
// Chunked associative scan, two passes (proven structure), fused dt-proj.
// ---------------------------------------------------------------------------
__global__ __launch_bounds__(256) void scanA_k(MP p, int i) {
    __shared__ float sXD[CL * DTR];
    __shared__ float sB[CL * NST];
    const int t = threadIdx.x;
    const int dx = blockIdx.x;
    const int y = blockIdx.y;
    const int b = y >> 1, br = y & 1;
    const int c = blockIdx.z;
    const int d = dx * 256 + t;
    const float* xc  = br ? p.xcb : p.xcf;
    const float* xdb = br ? p.xdbb : p.xdbf;
    const float* Al  = (br ? p.A_logb : p.A_log) + (size_t)i * DIN * NST;
    const float* dw  = (br ? p.dtproj_wb : p.dtproj_w) + (size_t)i * DIN * DTR;
    const float* dbi = (br ? p.dtproj_bb : p.dtproj_b) + (size_t)i * DIN;

    float An[NST];
    #pragma unroll
    for (int n = 0; n < NST; ++n) An[n] = -__expf(Al[(size_t)d * NST + n]);
    float wdt[DTR];
    #pragma unroll
    for (int k = 0; k < DTR; k += 4)
        *(float4*)&wdt[k] = *(const float4*)&dw[(size_t)d * DTR + k];
    float dbv = dbi[d];

    for (int idx = t; idx < CL * DTR; idx += 256) {
        int s0 = idx / DTR, j0 = idx - s0 * DTR;
        int l0 = c * CL + s0;
        sXD[s0 * DTR + j0] = (l0 < LF) ? xdb[(size_t)(b * LF + l0) * XDB + j0] : 0.f;
    }
    {
        int s0 = t >> 4, j0 = t & 15;
        int l0 = c * CL + s0;
        sB[s0 * NST + j0] = (l0 < LF) ? xdb[(size_t)(b * LF + l0) * XDB + DTR + j0] : 0.f;
    }
    __syncthreads();

    float h[NST] = {};
    float sdt = 0.f;
    #pragma unroll
    for (int s = 0; s < CL; ++s) {
        int l = c * CL + s;
        if (l < LF) {
            int row = b * LF + l;
            float dtv = dbv;
            #pragma unroll
            for (int k = 0; k < DTR; ++k) dtv += sXD[s * DTR + k] * wdt[k];
            dtv = softplusf(dtv);
            float xcv = xc[(size_t)row * DIN + d];
            sdt += dtv;
            float dtx = dtv * xcv;
            #pragma unroll
            for (int n = 0; n < NST; ++n)
                h[n] = __expf(dtv * An[n]) * h[n] + dtx * sB[s * NST + n];
        }
    }
    size_t base = (size_t)(c * 8 + y) * NST;
    #pragma unroll
    for (int n = 0; n < NST; ++n) p.hpart[(base + n) * DIN + d] = h[n];
    p.sumd[(size_t)(c * 8 + y) * DIN + d] = sdt;
}

__global__ __launch_bounds__(256) void scanC_k(MP p, int i) {
    __shared__ float sXD[CL * DTR];
    __shared__ float sB[CL * NST];
    __shared__ float sC[CL * NST];
    const int t = threadIdx.x;
    const int dx = blockIdx.x;
    const int y = blockIdx.y;
    const int b = y >> 1, br = y & 1;
    const int c = blockIdx.z;
    const int d = dx * 256 + t;
    const float* xc  = br ? p.xcb : p.xcf;
    const float* xdb = br ? p.xdbb : p.xdbf;
    const float* Al  = (br ? p.A_logb : p.A_log) + (size_t)i * DIN * NST;
    const float* Dpp = (br ? p.Dpb : p.Dp) + (size_t)i * DIN;
    const float* dw  = (br ? p.dtproj_wb : p.dtproj_w) + (size_t)i * DIN * DTR;
    const float* dbi = (br ? p.dtproj_bb : p.dtproj_b) + (size_t)i * DIN;
    float* yo = br ? p.ybb : p.yfb;

    float An[NST];
    #pragma unroll
    for (int n = 0; n < NST; ++n) An[n] = -__expf(Al[(size_t)d * NST + n]);
    float wdt[DTR];
    #pragma unroll
    for (int k = 0; k < DTR; k += 4)
        *(float4*)&wdt[k] = *(const float4*)&dw[(size_t)d * DTR + k];
    float dbv = dbi[d];
    float Dv = Dpp[d];

    for (int idx = t; idx < CL * DTR; idx += 256) {
        int s0 = idx / DTR, j0 = idx - s0 * DTR;
        int l0 = c * CL + s0;
        sXD[s0 * DTR + j0] = (l0 < LF) ? xdb[(size_t)(b * LF + l0) * XDB + j0] : 0.f;
    }
    {
        int s0 = t >> 4, j0 = t & 15;
        int l0 = c * CL + s0;
        size_t rb = (size_t)(b * LF + l0) * XDB + DTR;
        sB[s0 * NST + j0] = (l0 < LF) ? xdb[rb + j0] : 0.f;
        sC[s0 * NST + j0] = (l0 < LF) ? xdb[rb + NST + j0] : 0.f;
    }
    __syncthreads();

    // prefix combine, strip-mined x4 (loads of a group issue together)
    float h[NST] = {};
    for (int j0 = 0; j0 < c; j0 += 4) {
        float sd[4];
        float hp[4][NST];
        #pragma unroll
        for (int jj = 0; jj < 4; ++jj) {
            if (j0 + jj < c) {
                int j = j0 + jj;
                sd[jj] = p.sumd[(size_t)(j * 8 + y) * DIN + d];
                size_t base = (size_t)(j * 8 + y) * NST;
                #pragma unroll
                for (int n = 0; n < NST; ++n)
                    hp[jj][n] = p.hpart[(base + n) * DIN + d];
            }
        }
        #pragma unroll
        for (int jj = 0; jj < 4; ++jj) {
            if (j0 + jj < c) {
                #pragma unroll
                for (int n = 0; n < NST; ++n)
                    h[n] = __expf(An[n] * sd[jj]) * h[n] + hp[jj][n];
            }
        }
    }

    #pragma unroll
    for (int s = 0; s < CL; ++s) {
        int l = c * CL + s;
        if (l < LF) {
            int row = b * LF + l;
            float dtv = dbv;
            #pragma unroll
            for (int k = 0; k < DTR; ++k) dtv += sXD[s * DTR + k] * wdt[k];
            dtv = softplusf(dtv);
            float xcv = xc[(size_t)row * DIN + d];
            int zl = br ? (LF - 1 - l) : l;
            float zv = p.xz[(size_t)(b * LF + zl) * (2 * DIN) + DIN + d];
            float dtx = dtv * xcv;
            float acc = 0.f;
            #pragma unroll
            for (int n = 0; n < NST; ++n) {
                h[n] = __expf(dtv * An[n]) * h[n] + dtx * sB[s * NST + n];
                acc += h[n] * sC[s * NST + n];
            }
            yo[(size_t)row * DIN + d] = (acc + xcv * Dv) * siluf(zv);
        }
    }
}

// ---------------------------------------------------------------------------
// out_proj standalone wrapper (flip-add A, split-K atomics into residual)
// ---------------------------------------------------------------------------
template<int AMODE, int SMODE>
__global__ __launch_bounds__(256) void mgemm_k(
    const float* A, int lda, const float* W, const float* bias,
    float* Cout, int M, int N, int K, int KS,
    const float* gA, const float* A2, const float* pos)
{
    __shared__ __align__(16) short Ab[4096];
    __shared__ __align__(16) short Wb[4096];
    int ntile = blockIdx.y / KS, ks = blockIdx.y % KS;
    int chunk = K / KS;
    gemm_tile<AMODE, SMODE>(A, lda, W, bias, Cout, M, N, K,
                            ks * chunk, ks * chunk + chunk,
                            blockIdx.x * 64, ntile * 64, gA, A2, pos, Ab, Wb);
}

// final LN(row POS) + command MLP + add, 256 threads
__global__ __launch_bounds__(256) void final_k(MP p) {
    __shared__ float sm[416];
    float* hid   = sm;
    float* cmdin = sm + 384;
    float* red   = sm + 404;
    int b = blockIdx.x, t = threadIdx.x;
    const float* x = p.residual + (size_t)(b * LF + POSROW) * DMODEL;
    float v0 = x[t];
    float v1 = (t < 128) ? x[t + 256] : 0.f;
    float s = v0 + v1, sq = v0 * v0 + v1 * v1;
    #pragma unroll
    for (int o = 32; o > 0; o >>= 1) {
        s += __shfl_down(s, o);
        sq += __shfl_down(sq, o);
    }
    if ((t & 63) == 0) { red[t >> 6] = s; red[4 + (t >> 6)] = sq; }
    if (t < 20) cmdin[t] = (t < 16) ? p.state_vec[b * 16 + t] : p.action[b * 4 + t - 16];
    __syncthreads();
    float S = red[0] + red[1] + red[2] + red[3];
    float Q = red[4] + red[5] + red[6] + red[7];
    float mean = S * (1.f / 384.f);
    float var = Q * (1.f / 384.f) - mean * mean;
    float rs = rsqrtf(var + 1e-5f);
    {
        float a1 = p.cb1[t];
        #pragma unroll
        for (int k = 0; k < 20; ++k) a1 += cmdin[k] * p.cw1[t * 20 + k];
        hid[t] = fmaxf(a1, 0.f);
        if (t < 128) {
            int j = t + 256;
            float a1b = p.cb1[j];
            #pragma unroll
            for (int k = 0; k < 20; ++k) a1b += cmdin[k] * p.cw1[j * 20 + k];
            hid[j] = fmaxf(a1b, 0.f);
        }
    }
    __syncthreads();
    {
        float a2 = p.cb2[t];
        for (int k = 0; k < DMODEL; ++k) a2 += hid[k] * p.cw2[t * DMODEL + k];
        float vis = (v0 - mean) * rs * p.lnf_w[t] + p.lnf_b[t];
        p.out[b * DMODEL + t] = vis + a2;
        if (t < 128) {
            int j = t + 256;
            float a2b = p.cb2[j];
            for (int k = 0; k < DMODEL; ++k) a2b += hid[k] * p.cw2[j * DMODEL + k];
            float visb = (v1 - mean) * rs * p.lnf_w[j] + p.lnf_b[j];
            p.out[b * DMODEL + j] = visb + a2b;
        }
    }
}

extern "C" void kernel_launch(void* const* d_in, const int* in_sizes, int n_in,
                              void* d_out, int out_size, void* d_ws, size_t ws_size,
                              hipStream_t stream) {
    MP p;
    p.depth_seq = (const float*)d_in[0];
    p.state_vec = (const float*)d_in[1];
    p.action    = (const float*)d_in[2];
    p.patch_w   = (const float*)d_in[3];
    p.patch_b   = (const float*)d_in[4];
    p.cls_token = (const float*)d_in[5];
    p.pos_embed = (const float*)d_in[6];
    p.ln_w      = (const float*)d_in[7];
    p.ln_b      = (const float*)d_in[8];
    p.in_proj_w = (const float*)d_in[9];
    p.conv_w    = (const float*)d_in[10];
    p.conv_b    = (const float*)d_in[11];
    p.conv_wb   = (const float*)d_in[12];
    p.conv_bb   = (const float*)d_in[13];
    p.xproj_w   = (const float*)d_in[14];
    p.xproj_wb  = (const float*)d_in[15];
    p.dtproj_w  = (const float*)d_in[16];
    p.dtproj_b  = (const float*)d_in[17];
    p.dtproj_wb = (const float*)d_in[18];
    p.dtproj_bb = (const float*)d_in[19];
    p.A_log     = (const float*)d_in[20];
    p.A_logb    = (const float*)d_in[21];
    p.Dp        = (const float*)d_in[22];
    p.Dpb       = (const float*)d_in[23];
    p.out_w     = (const float*)d_in[24];
    p.lnf_w     = (const float*)d_in[25];
    p.lnf_b     = (const float*)d_in[26];
    p.cw1       = (const float*)d_in[27];
    p.cb1       = (const float*)d_in[28];
    p.cw2       = (const float*)d_in[29];
    p.cb2       = (const float*)d_in[30];

    float* ws = (float*)d_ws;
    size_t o = 0;
    p.residual = ws + o; o += (size_t)MROWS * DMODEL;
    p.xz       = ws + o; o += (size_t)MROWS * 2 * DIN;
    p.xcf      = ws + o; o += (size_t)MROWS * DIN;
    p.xcb      = ws + o; o += (size_t)MROWS * DIN;
    p.xdbf     = ws + o; o += (size_t)MROWS * XDB;
    p.xdbb     = ws + o; o += (size_t)MROWS * XDB;
    p.yfb      = ws + o; o += (size_t)MROWS * DIN;
    p.ybb      = ws + o; o += (size_t)MROWS * DIN;
    p.hpart    = ws + o; o += (size_t)NC * 8 * NST * DIN;
    p.sumd     = ws + o; o += (size_t)NC * 8 * DIN;
    p.out      = (float*)d_out;
    (void)ws_size; (void)in_sizes; (void)n_in; (void)out_size;

    patch_k<<<97, 256, 0, stream>>>(p);

    for (int i = 0; i < 4; ++i) {
        ip_k<<<408, 256, 0, stream>>>(p, i);
        hipMemsetAsync(p.xdbf, 0, (size_t)2 * MROWS * XDB * 4, stream);
        xp_k<<<dim3(17, 8, 2), 256, 0, stream>>>(p, i);
        scanA_k<<<dim3(3, 8, NC), 256, 0, stream>>>(p, i);
        scanC_k<<<dim3(3, 8, NC), 256, 0, stream>>>(p, i);
        mgemm_k<2, 4><<<dim3(17, 24), 256, 0, stream>>>(
            p.yfb, DIN, p.out_w + (size_t)i * DMODEL * DIN, nullptr,
            p.residual, MROWS, DMODEL, DIN, 4, nullptr, p.ybb, nullptr);
    }

    final_k<<<BB, 256, 0, stream>>>(p);
}